// Round 1
// baseline (920.763 us; speedup 1.0000x reference)
//
#include <hip/hip_runtime.h>
#include <hip/hip_bf16.h>

#define NN 10000
#define NE 320000
#define SIG 0.3f
#define NDp ((size_t)1280000)          // NN*128
#define OUT_H ((size_t)0)
#define OUT_E ((size_t)1280000)
#define OUT_P ((size_t)42240000)
#define OUT_D ((size_t)43520000)

// ws layout (float index): 8 node-linear outputs, fab, cnt, flags, staged bf16, CSR
#define F_V1H (0 * NDp)
#define F_V2H (1 * NDp)
#define F_P1H (2 * NDp)
#define F_P2H (3 * NDp)
#define F_P3H (4 * NDp)
#define F_D1H (5 * NDp)
#define F_D2H (6 * NDp)
#define F_G   (7 * NDp)
#define F_FAB (8 * NDp)
#define F_CNT (9 * NDp)
#define F_FLAGS (9 * NDp + 10240)       // 16 ints
#define F_STAGED (9 * NDp + 10240 + 16) // staged ushort region starts here
// staged (ushort index within staged region)
#define S_H  ((size_t)0)
#define S_P  ((size_t)1280000)
#define S_D  ((size_t)2560000)
#define S_W  ((size_t)3840000)          // 9 x 16384 (V1,V2,E1,P1,P2,P3,D1,D2,V)
#define S_WT (S_W + 9 * 16384)          // 32768
// staged region = S_WT + 32768 = 4020224 ushorts = 2010112 floats
#define F_DEG  (F_STAGED + (size_t)2010112)  // NN ints (in-degree, all edges)
#define F_OFF  (F_DEG + 10240)               // NN ints (exclusive scan)
#define F_FILL (F_OFF + 10240)               // NN ints (scatter cursors)
#define F_CSR  (F_FILL + 10240)              // NE ints (edge ids sorted by dst)

typedef __attribute__((ext_vector_type(8))) short s8v;
typedef __attribute__((ext_vector_type(4))) float f4v;

__device__ __forceinline__ float b2f(unsigned short s) {
  return __uint_as_float(((unsigned int)s) << 16);
}
__device__ __forceinline__ short f2b(float f) {
  __hip_bfloat16 b = __float2bfloat16(f);
  return *reinterpret_cast<short*>(&b);
}
__device__ __forceinline__ float lrelu(float x) { return x >= 0.f ? x : 0.01f * x; }
__device__ __forceinline__ float loadf(const void* p, size_t i, bool f32) {
  return f32 ? ((const float*)p)[i] : b2f(((const unsigned short*)p)[i]);
}
__device__ __forceinline__ void storef(void* p, size_t i, float v, bool f32) {
  if (f32) ((float*)p)[i] = v;
  else ((unsigned short*)p)[i] = (unsigned short)f2b(v);
}
__device__ __forceinline__ s8v cvt8(const float* fp) {
  s8v r;
#pragma unroll
  for (int j = 0; j < 8; j++) r[j] = f2b(fp[j]);
  return r;
}

// ---------------- zero fab/cnt/deg/fill/flags ----------------
__global__ __launch_bounds__(256) void zero_kernel(float* ws) {
  int i = blockIdx.x * 256 + threadIdx.x;  // grid = ND/256 exactly
  ws[F_FAB + i] = 0.f;
  if (i < NN) {
    ws[F_CNT + i] = 0.f;
    ((int*)(ws + F_DEG))[i] = 0;
    ((int*)(ws + F_FILL))[i] = 0;
  }
  if (i < 16) ((int*)(ws + F_FLAGS))[i] = 0;
}

// ---------------- dtype detection: bf16-NaN bit patterns <=> buffer is f32 ----------------
struct DetTask { const unsigned short* s; int n; int flag; };
struct DetArgs { DetTask t[6]; int* flags; };
__global__ __launch_bounds__(256) void detect_kernel(DetArgs a) {
  DetTask t = a.t[blockIdx.y];
  int hit = 0;
  for (int i = blockIdx.x * 256 + threadIdx.x; i < t.n; i += gridDim.x * 256) {
    if ((unsigned short)(t.s[i] & 0x7FFF) > (unsigned short)0x7F80) hit = 1;
  }
  if (hit) atomicOr(&a.flags[t.flag], 1);
}

// ---------------- stage tensors as canonical bf16 ----------------
struct ConvTask { const void* src; unsigned short* dst; int n; int flag; };
struct ConvArgs { ConvTask t[13]; const int* flags; };
__global__ __launch_bounds__(256) void convert_kernel(ConvArgs a) {
  ConvTask t = a.t[blockIdx.y];
  bool f32 = a.flags[t.flag] != 0;
  for (int i = blockIdx.x * 256 + threadIdx.x; i < t.n; i += gridDim.x * 256) {
    t.dst[i] = f32 ? (unsigned short)f2b(((const float*)t.src)[i])
                   : ((const unsigned short*)t.src)[i];
  }
}

// ---------------- per-dst counts: non-spatial (for sum_tau) + total degree (CSR) ----------------
__global__ __launch_bounds__(256) void cnt_kernel(const int* __restrict__ spatial,
                                                  const int* __restrict__ dst,
                                                  float* __restrict__ ws) {
  int e = blockIdx.x * 256 + threadIdx.x;
  if (e < NE) {
    int d = dst[e];
    atomicAdd((int*)(ws + F_DEG) + d, 1);
    if (spatial[e] != 1) atomicAdd(ws + F_CNT + d, 1.0f);
  }
}

// ---------------- exclusive scan of deg -> off (single block) ----------------
__global__ __launch_bounds__(1024) void scan_kernel(float* ws) {
  const int* deg = (const int*)(ws + F_DEG);
  int* off = (int*)(ws + F_OFF);
  __shared__ int sbuf[1024];
  __shared__ int carry;
  if (threadIdx.x == 0) carry = 0;
  __syncthreads();
  for (int base = 0; base < NN; base += 1024) {
    int i = base + threadIdx.x;
    int v = (i < NN) ? deg[i] : 0;
    sbuf[threadIdx.x] = v;
    __syncthreads();
#pragma unroll
    for (int ofs = 1; ofs < 1024; ofs <<= 1) {
      int t = (threadIdx.x >= ofs) ? sbuf[threadIdx.x - ofs] : 0;
      __syncthreads();
      sbuf[threadIdx.x] += t;
      __syncthreads();
    }
    int incl = sbuf[threadIdx.x];
    if (i < NN) off[i] = carry + incl - v;  // exclusive
    __syncthreads();
    if (threadIdx.x == 0) carry += sbuf[1023];
    __syncthreads();
  }
}

// ---------------- scatter edge ids into dst-sorted CSR ----------------
__global__ __launch_bounds__(256) void scatter_kernel(const int* __restrict__ dst,
                                                      float* __restrict__ ws) {
  int e = blockIdx.x * 256 + threadIdx.x;
  if (e < NE) {
    int d = dst[e];
    const int* off = (const int*)(ws + F_OFF);
    int* fill = (int*)(ws + F_FILL);
    int* csr = (int*)(ws + F_CSR);
    int pos = off[d] + atomicAdd(&fill[d], 1);
    csr[pos] = e;
  }
}

// ---------------- fused node linears (V1,V2,P1,P2,P3,D1,D2,T) ----------------
struct NodeArgs {
  const unsigned short* x[3];  // staged h, p, d
  const unsigned short* W[8];  // staged weights (bf16)
  const void* b[8];            // raw biases (adaptive)
  float* out[8];
  const int* flags;
};

__global__ __launch_bounds__(256) void node_gemm_kernel(NodeArgs a) {
  const int o = blockIdx.y;
  const int wave = threadIdx.x >> 6, lane = threadIdx.x & 63;
  const int l16 = lane & 15, quad = lane >> 4;
  const int m0 = blockIdx.x * 64 + wave * 16;
  if (m0 >= NN) return;
  const bool wf32 = a.flags[5] != 0;
  int arow = m0 + l16;
  if (arow >= NN) arow = NN - 1;
  const unsigned short* Wp = a.W[o];
  f4v acc[8] = {};
  if (o < 7) {
    const unsigned short* X0 = (o < 2) ? a.x[0] : (o < 5 ? a.x[1] : a.x[2]);
    const unsigned short* xrow = X0 + (size_t)arow * 128;
#pragma unroll
    for (int kk = 0; kk < 128; kk += 32) {
      int k8 = kk + quad * 8;
      s8v av = *(const s8v*)(xrow + k8);
#pragma unroll
      for (int nt = 0; nt < 8; nt++) {
        s8v bv = *(const s8v*)(Wp + (size_t)(nt * 16 + l16) * 128 + k8);
        acc[nt] = __builtin_amdgcn_mfma_f32_16x16x32_bf16(av, bv, acc[nt], 0, 0, 0);
      }
    }
  } else {  // W_T: K=256, input = [h | d]
#pragma unroll
    for (int kk = 0; kk < 256; kk += 32) {
      int k8 = kk + quad * 8;
      const unsigned short* ap = (k8 < 128) ? (a.x[0] + (size_t)arow * 128 + k8)
                                            : (a.x[2] + (size_t)arow * 128 + (k8 - 128));
      s8v av = *(const s8v*)ap;
#pragma unroll
      for (int nt = 0; nt < 8; nt++) {
        s8v bv = *(const s8v*)(Wp + (size_t)(nt * 16 + l16) * 256 + k8);
        acc[nt] = __builtin_amdgcn_mfma_f32_16x16x32_bf16(av, bv, acc[nt], 0, 0, 0);
      }
    }
  }
  float* outp = a.out[o];
#pragma unroll
  for (int nt = 0; nt < 8; nt++) {
    int col = nt * 16 + l16;
    float bvv = loadf(a.b[o], col, wf32);
#pragma unroll
    for (int r = 0; r < 4; r++) {
      int row = m0 + quad * 4 + r;
      if (row < NN) {
        float v = acc[nt][r] + bvv;
        if (o == 7) v = fmaxf(v, 0.f);
        outp[(size_t)row * 128 + col] = v;
      }
    }
  }
}

// ---------------- fused edge kernel (dst-sorted slot order) ----------------
__global__ __launch_bounds__(256) void edge_kernel(
    const void* __restrict__ e, const unsigned short* __restrict__ sh,
    const int* __restrict__ spatial, const int* __restrict__ src, const int* __restrict__ dst,
    const unsigned short* __restrict__ WE1, const unsigned short* __restrict__ WV,
    const void* __restrict__ bE1, const void* __restrict__ bV,
    const float* __restrict__ P1h, const float* __restrict__ P2h,
    float* __restrict__ fab, void* __restrict__ out, const int* __restrict__ flags,
    const int* __restrict__ csr) {
  const int wave = threadIdx.x >> 6, lane = threadIdx.x & 63;
  const int l16 = lane & 15, quad = lane >> 4;
  const int m0 = blockIdx.x * 64 + wave * 16;  // NE % 64 == 0
  const bool ef32 = flags[1] != 0;
  const bool wf32 = flags[5] != 0;
  const bool of32 = (flags[0] | flags[1] | flags[2] | flags[3] | flags[4] | flags[5]) != 0;

  const int eidA = csr[m0 + l16];  // A-row edge id (slot -> edge)

  // Phase A: Vj GEMM first, reduced to sv immediately (frees its accumulators
  // before the E1 accumulators go live -> lower peak regs -> higher occupancy)
  float sv[4];
  {
    f4v acc2[8] = {};
    const int asrc = src[eidA], adst = dst[eidA];
    const unsigned short* hs_row = sh + (size_t)asrc * 128;
    const unsigned short* hd_row = sh + (size_t)adst * 128;
#pragma unroll
    for (int kk = 0; kk < 128; kk += 32) {
      int k8 = kk + quad * 8;
      s8v hs = *(const s8v*)(hs_row + k8);
      s8v hd = *(const s8v*)(hd_row + k8);
      s8v ap;
#pragma unroll
      for (int j = 0; j < 8; j++)
        ap[j] = f2b(b2f((unsigned short)hs[j]) * b2f((unsigned short)hd[j]));
#pragma unroll
      for (int nt = 0; nt < 8; nt++) {
        s8v bv = *(const s8v*)(WV + (size_t)(nt * 16 + l16) * 128 + k8);
        acc2[nt] = __builtin_amdgcn_mfma_f32_16x16x32_bf16(ap, bv, acc2[nt], 0, 0, 0);
      }
    }
    sv[0] = sv[1] = sv[2] = sv[3] = 0.f;
#pragma unroll
    for (int nt = 0; nt < 8; nt++) {
      int col = nt * 16 + l16;
      float bvv = loadf(bV, col, wf32);
#pragma unroll
      for (int r = 0; r < 4; r++) sv[r] += fmaxf(acc2[nt][r] + bvv, 0.f);
    }
#pragma unroll
    for (int m = 1; m < 16; m <<= 1) {
#pragma unroll
      for (int r = 0; r < 4; r++) sv[r] += __shfl_xor(sv[r], m, 64);
    }
  }

  // Phase B: E1e GEMM (adaptive A-load from e via CSR indirection)
  f4v acc1[8] = {};
  {
    size_t ro = (size_t)eidA * 128;
#pragma unroll
    for (int kk = 0; kk < 128; kk += 32) {
      int k8 = kk + quad * 8;
      s8v av;
      if (ef32) av = cvt8((const float*)e + ro + k8);
      else av = *(const s8v*)((const unsigned short*)e + ro + k8);
#pragma unroll
      for (int nt = 0; nt < 8; nt++) {
        s8v bv = *(const s8v*)(WE1 + (size_t)(nt * 16 + l16) * 128 + k8);
        acc1[nt] = __builtin_amdgcn_mfma_f32_16x16x32_bf16(av, bv, acc1[nt], 0, 0, 0);
      }
    }
  }

  // Epilogue rows: slot = m0 + quad*4 + r (dst non-decreasing in slot order)
  int er[4], sr[4], dr[4], sp[4];
#pragma unroll
  for (int r = 0; r < 4; r++) {
    int slot = m0 + quad * 4 + r;
    er[r] = csr[slot];
    sr[r] = src[er[r]];
    dr[r] = dst[er[r]];
    sp[r] = spatial[er[r]];
  }
  float en[8][4];
  float nrm2[4] = {0.f, 0.f, 0.f, 0.f};
#pragma unroll
  for (int nt = 0; nt < 8; nt++) {
    int col = nt * 16 + l16;
    float be = loadf(bE1, col, wf32);
#pragma unroll
    for (int r = 0; r < 4; r++) {
      float E1 = acc1[nt][r] + be;
      float v = 0.5f * (P1h[(size_t)dr[r] * 128 + col] - P2h[(size_t)sr[r] * 128 + col] + E1);
      en[nt][r] = v;
      nrm2[r] += v * v;
      float eo = loadf(e, (size_t)er[r] * 128 + col, ef32);
      storef(out, OUT_E + (size_t)er[r] * 128 + col, eo + lrelu(v), of32);
    }
  }
#pragma unroll
  for (int m = 1; m < 16; m <<= 1) {
#pragma unroll
    for (int r = 0; r < 4; r++) nrm2[r] += __shfl_xor(nrm2[r], m, 64);
  }
  float coef[4];
#pragma unroll
  for (int r = 0; r < 4; r++) {
    float n = sqrtf(nrm2[r]);
    float c = 0.f;
    if (sp[r] == 1 && n >= 1e-9f) {
      float rr = 0.5f * sqrtf(n);
      float s = expf(-rr / SIG);
      c = -sv[r] * s * 0.25f / (SIG * n * sqrtf(n));
    }
    coef[r] = c;
  }
  // dst-sorted => dr monotone within quad; dr[0]==dr[3] <=> uniform quad.
  // Merge the 4 rows' fab contributions into one atomic per col (4x fewer RMWs).
  bool any = (coef[0] != 0.f) | (coef[1] != 0.f) | (coef[2] != 0.f) | (coef[3] != 0.f);
  if (dr[0] == dr[3]) {
    if (any) {
      size_t base = (size_t)dr[0] * 128;
#pragma unroll
      for (int nt = 0; nt < 8; nt++) {
        int col = nt * 16 + l16;
        float val = coef[0] * en[nt][0] + coef[1] * en[nt][1] +
                    coef[2] * en[nt][2] + coef[3] * en[nt][3];
        atomicAdd(&fab[base + col], val);
      }
    }
  } else {
#pragma unroll
    for (int r = 0; r < 4; r++) {
      if (coef[r] != 0.f) {
#pragma unroll
        for (int nt = 0; nt < 8; nt++) {
          int col = nt * 16 + l16;
          atomicAdd(&fab[(size_t)dr[r] * 128 + col], coef[r] * en[nt][r]);
        }
      }
    }
  }
}

// ---------------- node finalize ----------------
__global__ __launch_bounds__(256) void node_out_kernel(
    const unsigned short* __restrict__ sh, const unsigned short* __restrict__ sp,
    const unsigned short* __restrict__ sd, const void* __restrict__ dt,
    const float* __restrict__ V1h, const float* __restrict__ V2h, const float* __restrict__ P3h,
    const float* __restrict__ D1h, const float* __restrict__ D2h, const float* __restrict__ g,
    const float* __restrict__ fab, const float* __restrict__ cnt,
    void* __restrict__ out, const int* __restrict__ flags) {
  const int wave = threadIdx.x >> 6, lane = threadIdx.x & 63;
  const int node = blockIdx.x * 4 + wave;  // NN % 4 == 0
  const bool dtf32 = flags[4] != 0;
  const bool of32 = (flags[0] | flags[1] | flags[2] | flags[3] | flags[4] | flags[5]) != 0;
  const size_t i = (size_t)node * 128 + lane * 2;
  float cn = cnt[node];
  float2 v1 = *(const float2*)(V1h + i);
  float2 d1 = *(const float2*)(D1h + i);
  float2 gg = *(const float2*)(g + i);
  float2 fb = *(const float2*)(fab + i);
  float fx = (d1.x - v1.x) * (cn * gg.x) - fb.x;
  float fy = (d1.y - v1.y) * (cn * gg.y) - fb.y;
  float n2 = fx * fx + fy * fy;
#pragma unroll
  for (int m = 1; m < 64; m <<= 1) n2 += __shfl_xor(n2, m, 64);
  float nf = sqrtf(n2);
  float dtv = loadf(dt, node, dtf32);
  float2 v2 = *(const float2*)(V2h + i);
  float2 p3 = *(const float2*)(P3h + i);
  float2 d2 = *(const float2*)(D2h + i);
  float hx = v2.x + fx * dtv, hy = v2.y + fy * dtv;
  float px = p3.x + fx * dtv + 0.5f * fx * dtv * dtv;
  float py = p3.y + fy * dtv + 0.5f * fy * dtv * dtv;
  float invn = 1.f / (nf + 1e-9f);
  float dx = d2.x + fx * invn, dy = d2.y + fy * invn;
  storef(out, OUT_H + i,     b2f(sh[i])     + lrelu(hx), of32);
  storef(out, OUT_H + i + 1, b2f(sh[i + 1]) + lrelu(hy), of32);
  storef(out, OUT_P + i,     b2f(sp[i])     + lrelu(px), of32);
  storef(out, OUT_P + i + 1, b2f(sp[i + 1]) + lrelu(py), of32);
  storef(out, OUT_D + i,     b2f(sd[i])     + lrelu(dx), of32);
  storef(out, OUT_D + i + 1, b2f(sd[i + 1]) + lrelu(dy), of32);
}

extern "C" void kernel_launch(void* const* d_in, const int* in_sizes, int n_in,
                              void* d_out, int out_size, void* d_ws, size_t ws_size,
                              hipStream_t stream) {
  const int* spatial = (const int*)d_in[5];
  const int* src = (const int*)d_in[6];
  const int* dst = (const int*)d_in[7];

  float* ws = (float*)d_ws;
  int* flags = (int*)(ws + F_FLAGS);
  unsigned short* stg = (unsigned short*)(ws + F_STAGED);

  zero_kernel<<<(int)(NDp / 256), 256, 0, stream>>>(ws);

  DetArgs da;
  da.t[0] = { (const unsigned short*)d_in[0], 1280000, 0 };
  da.t[1] = { (const unsigned short*)d_in[1], 40960000, 1 };
  da.t[2] = { (const unsigned short*)d_in[2], 1280000, 2 };
  da.t[3] = { (const unsigned short*)d_in[3], 1280000, 3 };
  da.t[4] = { (const unsigned short*)d_in[4], 10000, 4 };
  da.t[5] = { (const unsigned short*)d_in[8], 16384, 5 };
  da.flags = flags;
  detect_kernel<<<dim3(1024, 6), 256, 0, stream>>>(da);

  ConvArgs ca;
  ca.t[0] = { d_in[0], stg + S_H, 1280000, 0 };
  ca.t[1] = { d_in[2], stg + S_P, 1280000, 2 };
  ca.t[2] = { d_in[3], stg + S_D, 1280000, 3 };
  for (int i = 0; i < 9; i++)
    ca.t[3 + i] = { d_in[8 + 2 * i], stg + S_W + (size_t)i * 16384, 16384, 5 };
  ca.t[12] = { d_in[26], stg + S_WT, 32768, 5 };
  ca.flags = flags;
  convert_kernel<<<dim3(640, 13), 256, 0, stream>>>(ca);

  cnt_kernel<<<NE / 256, 256, 0, stream>>>(spatial, dst, ws);
  scan_kernel<<<1, 1024, 0, stream>>>(ws);
  scatter_kernel<<<NE / 256, 256, 0, stream>>>(dst, ws);

  NodeArgs na;
  na.x[0] = stg + S_H; na.x[1] = stg + S_P; na.x[2] = stg + S_D;
  na.W[0] = stg + S_W + 0 * 16384;  na.b[0] = d_in[9];   // V1
  na.W[1] = stg + S_W + 1 * 16384;  na.b[1] = d_in[11];  // V2
  na.W[2] = stg + S_W + 3 * 16384;  na.b[2] = d_in[15];  // P1
  na.W[3] = stg + S_W + 4 * 16384;  na.b[3] = d_in[17];  // P2
  na.W[4] = stg + S_W + 5 * 16384;  na.b[4] = d_in[19];  // P3
  na.W[5] = stg + S_W + 6 * 16384;  na.b[5] = d_in[21];  // D1
  na.W[6] = stg + S_W + 7 * 16384;  na.b[6] = d_in[23];  // D2
  na.W[7] = stg + S_WT;             na.b[7] = d_in[27];  // T
  na.out[0] = ws + F_V1H; na.out[1] = ws + F_V2H; na.out[2] = ws + F_P1H;
  na.out[3] = ws + F_P2H; na.out[4] = ws + F_P3H; na.out[5] = ws + F_D1H;
  na.out[6] = ws + F_D2H; na.out[7] = ws + F_G;
  na.flags = flags;
  node_gemm_kernel<<<dim3((NN + 63) / 64, 8), 256, 0, stream>>>(na);

  edge_kernel<<<NE / 64, 256, 0, stream>>>(
      d_in[1], stg + S_H, spatial, src, dst,
      stg + S_W + 2 * 16384, stg + S_W + 8 * 16384, d_in[13], d_in[25],
      ws + F_P1H, ws + F_P2H, ws + F_FAB, d_out, flags,
      (const int*)(ws + F_CSR));

  node_out_kernel<<<NN / 4, 256, 0, stream>>>(
      stg + S_H, stg + S_P, stg + S_D, d_in[4],
      ws + F_V1H, ws + F_V2H, ws + F_P3H, ws + F_D1H, ws + F_D2H, ws + F_G,
      ws + F_FAB, ws + F_CNT, d_out, flags);
}

// Round 2
// 828.869 us; speedup vs baseline: 1.1109x; 1.1109x over previous
//
#include <hip/hip_runtime.h>
#include <hip/hip_bf16.h>

#define NN 10000
#define NE 320000
#define SIG 0.3f
#define NDp ((size_t)1280000)          // NN*128
#define OUT_H ((size_t)0)
#define OUT_E ((size_t)1280000)
#define OUT_P ((size_t)42240000)
#define OUT_D ((size_t)43520000)

// ws layout (float index): 8 node-linear outputs, fab, cnt, flags, staged bf16
#define F_V1H (0 * NDp)
#define F_V2H (1 * NDp)
#define F_P1H (2 * NDp)
#define F_P2H (3 * NDp)
#define F_P3H (4 * NDp)
#define F_D1H (5 * NDp)
#define F_D2H (6 * NDp)
#define F_G   (7 * NDp)
#define F_FAB (8 * NDp)
#define F_CNT (9 * NDp)
#define F_FLAGS (9 * NDp + 10240)       // 16 ints
#define F_STAGED (9 * NDp + 10240 + 16) // staged ushort region starts here
// staged (ushort index within staged region)
#define S_H  ((size_t)0)
#define S_P  ((size_t)1280000)
#define S_D  ((size_t)2560000)
#define S_W  ((size_t)3840000)          // 9 x 16384 (V1,V2,E1,P1,P2,P3,D1,D2,V)
#define S_WT (S_W + 9 * 16384)          // 32768

typedef __attribute__((ext_vector_type(8))) short s8v;
typedef __attribute__((ext_vector_type(4))) float f4v;

__device__ __forceinline__ float b2f(unsigned short s) {
  return __uint_as_float(((unsigned int)s) << 16);
}
__device__ __forceinline__ short f2b(float f) {
  __hip_bfloat16 b = __float2bfloat16(f);
  return *reinterpret_cast<short*>(&b);
}
__device__ __forceinline__ float lrelu(float x) { return x >= 0.f ? x : 0.01f * x; }
__device__ __forceinline__ float loadf(const void* p, size_t i, bool f32) {
  return f32 ? ((const float*)p)[i] : b2f(((const unsigned short*)p)[i]);
}
__device__ __forceinline__ void storef(void* p, size_t i, float v, bool f32) {
  if (f32) ((float*)p)[i] = v;
  else ((unsigned short*)p)[i] = (unsigned short)f2b(v);
}
// paired store (i even): float2 or packed 2xbf16
__device__ __forceinline__ void storef2(void* p, size_t i, float x, float y, bool f32) {
  if (f32) {
    *reinterpret_cast<float2*>((float*)p + i) = make_float2(x, y);
  } else {
    unsigned int v = ((unsigned int)(unsigned short)f2b(y) << 16) |
                     (unsigned int)(unsigned short)f2b(x);
    *((unsigned int*)p + (i >> 1)) = v;
  }
}
// vectorized f32->bf16x8 (16B-aligned src)
__device__ __forceinline__ s8v cvt8(const float* fp) {
  f4v a = *reinterpret_cast<const f4v*>(fp);
  f4v b = *reinterpret_cast<const f4v*>(fp + 4);
  s8v r;
#pragma unroll
  for (int j = 0; j < 4; j++) { r[j] = f2b(a[j]); r[4 + j] = f2b(b[j]); }
  return r;
}

// ---------------- zero fab/cnt/flags ----------------
__global__ __launch_bounds__(256) void zero_kernel(float* ws) {
  int i = blockIdx.x * 256 + threadIdx.x;  // grid = ND/256 exactly
  ws[F_FAB + i] = 0.f;
  if (i < NN) ws[F_CNT + i] = 0.f;
  if (i < 16) ((int*)(ws + F_FLAGS))[i] = 0;
}

// ---------------- dtype detection: bf16-NaN bit patterns <=> buffer is f32 ----------------
struct DetTask { const unsigned short* s; int n; int flag; };
struct DetArgs { DetTask t[6]; int* flags; };
__global__ __launch_bounds__(256) void detect_kernel(DetArgs a) {
  DetTask t = a.t[blockIdx.y];
  int hit = 0;
  for (int i = blockIdx.x * 256 + threadIdx.x; i < t.n; i += gridDim.x * 256) {
    if ((unsigned short)(t.s[i] & 0x7FFF) > (unsigned short)0x7F80) hit = 1;
  }
  if (hit) atomicOr(&a.flags[t.flag], 1);
}

// ---------------- stage tensors as canonical bf16 ----------------
struct ConvTask { const void* src; unsigned short* dst; int n; int flag; };
struct ConvArgs { ConvTask t[13]; const int* flags; };
__global__ __launch_bounds__(256) void convert_kernel(ConvArgs a) {
  ConvTask t = a.t[blockIdx.y];
  bool f32 = a.flags[t.flag] != 0;
  for (int i = blockIdx.x * 256 + threadIdx.x; i < t.n; i += gridDim.x * 256) {
    t.dst[i] = f32 ? (unsigned short)f2b(((const float*)t.src)[i])
                   : ((const unsigned short*)t.src)[i];
  }
}

// ---------------- count non-spatial in-edges per dst ----------------
__global__ __launch_bounds__(256) void cnt_kernel(const int* __restrict__ spatial,
                                                  const int* __restrict__ dst,
                                                  float* __restrict__ cnt) {
  int e = blockIdx.x * 256 + threadIdx.x;
  if (e < NE && spatial[e] != 1) atomicAdd(&cnt[dst[e]], 1.0f);
}

// ---------------- fused node linears (V1,V2,P1,P2,P3,D1,D2,T) ----------------
struct NodeArgs {
  const unsigned short* x[3];  // staged h, p, d
  const unsigned short* W[8];  // staged weights (bf16)
  const void* b[8];            // raw biases (adaptive)
  float* out[8];
  const int* flags;
};

__global__ __launch_bounds__(256) void node_gemm_kernel(NodeArgs a) {
  const int o = blockIdx.y;
  const int wave = threadIdx.x >> 6, lane = threadIdx.x & 63;
  const int l16 = lane & 15, quad = lane >> 4;
  const int m0 = blockIdx.x * 64 + wave * 16;
  if (m0 >= NN) return;
  const bool wf32 = a.flags[5] != 0;
  int arow = m0 + l16;
  if (arow >= NN) arow = NN - 1;
  const unsigned short* Wp = a.W[o];
  f4v acc[8] = {};
  if (o < 7) {
    const unsigned short* X0 = (o < 2) ? a.x[0] : (o < 5 ? a.x[1] : a.x[2]);
    const unsigned short* xrow = X0 + (size_t)arow * 128;
#pragma unroll
    for (int kk = 0; kk < 128; kk += 32) {
      int k8 = kk + quad * 8;
      s8v av = *(const s8v*)(xrow + k8);
#pragma unroll
      for (int nt = 0; nt < 8; nt++) {
        s8v bv = *(const s8v*)(Wp + (size_t)(nt * 16 + l16) * 128 + k8);
        acc[nt] = __builtin_amdgcn_mfma_f32_16x16x32_bf16(av, bv, acc[nt], 0, 0, 0);
      }
    }
  } else {  // W_T: K=256, input = [h | d]
#pragma unroll
    for (int kk = 0; kk < 256; kk += 32) {
      int k8 = kk + quad * 8;
      const unsigned short* ap = (k8 < 128) ? (a.x[0] + (size_t)arow * 128 + k8)
                                            : (a.x[2] + (size_t)arow * 128 + (k8 - 128));
      s8v av = *(const s8v*)ap;
#pragma unroll
      for (int nt = 0; nt < 8; nt++) {
        s8v bv = *(const s8v*)(Wp + (size_t)(nt * 16 + l16) * 256 + k8);
        acc[nt] = __builtin_amdgcn_mfma_f32_16x16x32_bf16(av, bv, acc[nt], 0, 0, 0);
      }
    }
  }
  float* outp = a.out[o];
#pragma unroll
  for (int nt = 0; nt < 8; nt++) {
    int col = nt * 16 + l16;
    float bvv = loadf(a.b[o], col, wf32);
#pragma unroll
    for (int r = 0; r < 4; r++) {
      int row = m0 + quad * 4 + r;
      if (row < NN) {
        float v = acc[nt][r] + bvv;
        if (o == 7) v = fmaxf(v, 0.f);
        outp[(size_t)row * 128 + col] = v;
      }
    }
  }
}

// ---------------- fused edge kernel ----------------
// Per wave: 16 edges (sequential). Phase A: Vj GEMM -> sv (LDS). Phase B: E1
// GEMM, staging e-tile (from A-fragments) and E1 (bf16) into per-wave LDS.
// Epilogue: row loop with wave-uniform indices, 2 cols/lane -> coalesced
// float2 gathers of P1h/P2h, coalesced out_E stores, row-uniform atomics.
#define LSTRIDE 136  // 128 + 8 pad (ushorts) -> 272B rows, 2-way max conflict
__global__ __launch_bounds__(256) void edge_kernel(
    const void* __restrict__ e, const unsigned short* __restrict__ sh,
    const int* __restrict__ spatial, const int* __restrict__ src, const int* __restrict__ dst,
    const unsigned short* __restrict__ WE1, const unsigned short* __restrict__ WV,
    const void* __restrict__ bE1, const void* __restrict__ bV,
    const float* __restrict__ P1h, const float* __restrict__ P2h,
    float* __restrict__ fab, void* __restrict__ out, const int* __restrict__ flags) {
  __shared__ __align__(16) unsigned short lds_e[4][16 * LSTRIDE];
  __shared__ __align__(16) unsigned short lds_E1[4][16 * LSTRIDE];
  __shared__ float lds_sv[4][16];
  const int wave = threadIdx.x >> 6, lane = threadIdx.x & 63;
  const int l16 = lane & 15, quad = lane >> 4;
  const int m0 = blockIdx.x * 64 + wave * 16;  // NE % 64 == 0
  const bool ef32 = flags[1] != 0;
  const bool wf32 = flags[5] != 0;
  const bool of32 = (flags[0] | flags[1] | flags[2] | flags[3] | flags[4] | flags[5]) != 0;
  const int arow = m0 + l16;

  // ---- Phase A: Vj GEMM, reduced immediately to sv, parked in LDS ----
  {
    f4v acc2[8] = {};
    const int asrc = src[arow], adst = dst[arow];
    const unsigned short* hs_row = sh + (size_t)asrc * 128;
    const unsigned short* hd_row = sh + (size_t)adst * 128;
#pragma unroll
    for (int kk = 0; kk < 128; kk += 32) {
      int k8 = kk + quad * 8;
      s8v hs = *(const s8v*)(hs_row + k8);
      s8v hd = *(const s8v*)(hd_row + k8);
      s8v ap;
#pragma unroll
      for (int j = 0; j < 8; j++)
        ap[j] = f2b(b2f((unsigned short)hs[j]) * b2f((unsigned short)hd[j]));
#pragma unroll
      for (int nt = 0; nt < 8; nt++) {
        s8v bv = *(const s8v*)(WV + (size_t)(nt * 16 + l16) * 128 + k8);
        acc2[nt] = __builtin_amdgcn_mfma_f32_16x16x32_bf16(ap, bv, acc2[nt], 0, 0, 0);
      }
    }
    float sv[4] = {0.f, 0.f, 0.f, 0.f};
#pragma unroll
    for (int nt = 0; nt < 8; nt++) {
      int col = nt * 16 + l16;
      float bvv = loadf(bV, col, wf32);
#pragma unroll
      for (int r = 0; r < 4; r++) sv[r] += fmaxf(acc2[nt][r] + bvv, 0.f);
    }
#pragma unroll
    for (int m = 1; m < 16; m <<= 1) {
#pragma unroll
      for (int r = 0; r < 4; r++) sv[r] += __shfl_xor(sv[r], m, 64);
    }
    if (l16 == 0) {
#pragma unroll
      for (int r = 0; r < 4; r++) lds_sv[wave][quad * 4 + r] = sv[r];
    }
  }

  // ---- Phase B: E1 GEMM; stage e-tile (bf16) + E1 (bf16) into LDS ----
  {
    f4v acc1[8] = {};
    size_t ro = (size_t)arow * 128;
#pragma unroll
    for (int kk = 0; kk < 128; kk += 32) {
      int k8 = kk + quad * 8;
      s8v av;
      if (ef32) av = cvt8((const float*)e + ro + k8);
      else av = *(const s8v*)((const unsigned short*)e + ro + k8);
      *(s8v*)&lds_e[wave][l16 * LSTRIDE + k8] = av;  // stage: read e ONCE
#pragma unroll
      for (int nt = 0; nt < 8; nt++) {
        s8v bv = *(const s8v*)(WE1 + (size_t)(nt * 16 + l16) * 128 + k8);
        acc1[nt] = __builtin_amdgcn_mfma_f32_16x16x32_bf16(av, bv, acc1[nt], 0, 0, 0);
      }
    }
#pragma unroll
    for (int nt = 0; nt < 8; nt++) {
      int col = nt * 16 + l16;
      float bvv = loadf(bE1, col, wf32);
#pragma unroll
      for (int r = 0; r < 4; r++) {
        int row = quad * 4 + r;
        lds_E1[wave][row * LSTRIDE + col] = (unsigned short)f2b(acc1[nt][r] + bvv);
      }
    }
  }
  // per-wave LDS only: same-wave write->read, compiler inserts lgkmcnt waits

  // ---- Epilogue: 16 rows, wave-uniform indices, 2 cols per lane ----
  const int c0 = lane * 2;
#pragma unroll 4
  for (int row = 0; row < 16; row++) {
    const int er = m0 + row;
    const int sr_ = src[er], dr_ = dst[er], sp_ = spatial[er];  // uniform
    float2 p1 = *(const float2*)(P1h + (size_t)dr_ * 128 + c0);
    float2 p2 = *(const float2*)(P2h + (size_t)sr_ * 128 + c0);
    unsigned int e1w = *(const unsigned int*)&lds_E1[wave][row * LSTRIDE + c0];
    unsigned int eew = *(const unsigned int*)&lds_e[wave][row * LSTRIDE + c0];
    float e1x = b2f((unsigned short)(e1w & 0xFFFF));
    float e1y = b2f((unsigned short)(e1w >> 16));
    float eex = b2f((unsigned short)(eew & 0xFFFF));
    float eey = b2f((unsigned short)(eew >> 16));
    float vx = 0.5f * (p1.x - p2.x + e1x);
    float vy = 0.5f * (p1.y - p2.y + e1y);
    storef2(out, OUT_E + (size_t)er * 128 + c0, eex + lrelu(vx), eey + lrelu(vy), of32);
    float n2 = vx * vx + vy * vy;
#pragma unroll
    for (int m = 1; m < 64; m <<= 1) n2 += __shfl_xor(n2, m, 64);
    if (sp_ == 1) {
      float n = sqrtf(n2);
      if (n >= 1e-9f) {
        float svr = lds_sv[wave][row];
        float rr = 0.5f * sqrtf(n);
        float s = expf(-rr / SIG);
        float c = -svr * s * 0.25f / (SIG * n * sqrtf(n));
        atomicAdd(&fab[(size_t)dr_ * 128 + c0], c * vx);
        atomicAdd(&fab[(size_t)dr_ * 128 + c0 + 1], c * vy);
      }
    }
  }
}

// ---------------- node finalize ----------------
__global__ __launch_bounds__(256) void node_out_kernel(
    const unsigned short* __restrict__ sh, const unsigned short* __restrict__ sp,
    const unsigned short* __restrict__ sd, const void* __restrict__ dt,
    const float* __restrict__ V1h, const float* __restrict__ V2h, const float* __restrict__ P3h,
    const float* __restrict__ D1h, const float* __restrict__ D2h, const float* __restrict__ g,
    const float* __restrict__ fab, const float* __restrict__ cnt,
    void* __restrict__ out, const int* __restrict__ flags) {
  const int wave = threadIdx.x >> 6, lane = threadIdx.x & 63;
  const int node = blockIdx.x * 4 + wave;  // NN % 4 == 0
  const bool dtf32 = flags[4] != 0;
  const bool of32 = (flags[0] | flags[1] | flags[2] | flags[3] | flags[4] | flags[5]) != 0;
  const size_t i = (size_t)node * 128 + lane * 2;
  float cn = cnt[node];
  float2 v1 = *(const float2*)(V1h + i);
  float2 d1 = *(const float2*)(D1h + i);
  float2 gg = *(const float2*)(g + i);
  float2 fb = *(const float2*)(fab + i);
  float fx = (d1.x - v1.x) * (cn * gg.x) - fb.x;
  float fy = (d1.y - v1.y) * (cn * gg.y) - fb.y;
  float n2 = fx * fx + fy * fy;
#pragma unroll
  for (int m = 1; m < 64; m <<= 1) n2 += __shfl_xor(n2, m, 64);
  float nf = sqrtf(n2);
  float dtv = loadf(dt, node, dtf32);
  float2 v2 = *(const float2*)(V2h + i);
  float2 p3 = *(const float2*)(P3h + i);
  float2 d2 = *(const float2*)(D2h + i);
  float hx = v2.x + fx * dtv, hy = v2.y + fy * dtv;
  float px = p3.x + fx * dtv + 0.5f * fx * dtv * dtv;
  float py = p3.y + fy * dtv + 0.5f * fy * dtv * dtv;
  float invn = 1.f / (nf + 1e-9f);
  float dx = d2.x + fx * invn, dy = d2.y + fy * invn;
  storef2(out, OUT_H + i, b2f(sh[i]) + lrelu(hx), b2f(sh[i + 1]) + lrelu(hy), of32);
  storef2(out, OUT_P + i, b2f(sp[i]) + lrelu(px), b2f(sp[i + 1]) + lrelu(py), of32);
  storef2(out, OUT_D + i, b2f(sd[i]) + lrelu(dx), b2f(sd[i + 1]) + lrelu(dy), of32);
}

extern "C" void kernel_launch(void* const* d_in, const int* in_sizes, int n_in,
                              void* d_out, int out_size, void* d_ws, size_t ws_size,
                              hipStream_t stream) {
  const int* spatial = (const int*)d_in[5];
  const int* src = (const int*)d_in[6];
  const int* dst = (const int*)d_in[7];

  float* ws = (float*)d_ws;
  int* flags = (int*)(ws + F_FLAGS);
  unsigned short* stg = (unsigned short*)(ws + F_STAGED);

  zero_kernel<<<(int)(NDp / 256), 256, 0, stream>>>(ws);

  DetArgs da;
  da.t[0] = { (const unsigned short*)d_in[0], 1280000, 0 };
  da.t[1] = { (const unsigned short*)d_in[1], 40960000, 1 };
  da.t[2] = { (const unsigned short*)d_in[2], 1280000, 2 };
  da.t[3] = { (const unsigned short*)d_in[3], 1280000, 3 };
  da.t[4] = { (const unsigned short*)d_in[4], 10000, 4 };
  da.t[5] = { (const unsigned short*)d_in[8], 16384, 5 };
  da.flags = flags;
  detect_kernel<<<dim3(1024, 6), 256, 0, stream>>>(da);

  ConvArgs ca;
  ca.t[0] = { d_in[0], stg + S_H, 1280000, 0 };
  ca.t[1] = { d_in[2], stg + S_P, 1280000, 2 };
  ca.t[2] = { d_in[3], stg + S_D, 1280000, 3 };
  for (int i = 0; i < 9; i++)
    ca.t[3 + i] = { d_in[8 + 2 * i], stg + S_W + (size_t)i * 16384, 16384, 5 };
  ca.t[12] = { d_in[26], stg + S_WT, 32768, 5 };
  ca.flags = flags;
  convert_kernel<<<dim3(640, 13), 256, 0, stream>>>(ca);

  cnt_kernel<<<NE / 256, 256, 0, stream>>>(spatial, dst, ws + F_CNT);

  NodeArgs na;
  na.x[0] = stg + S_H; na.x[1] = stg + S_P; na.x[2] = stg + S_D;
  na.W[0] = stg + S_W + 0 * 16384;  na.b[0] = d_in[9];   // V1
  na.W[1] = stg + S_W + 1 * 16384;  na.b[1] = d_in[11];  // V2
  na.W[2] = stg + S_W + 3 * 16384;  na.b[2] = d_in[15];  // P1
  na.W[3] = stg + S_W + 4 * 16384;  na.b[3] = d_in[17];  // P2
  na.W[4] = stg + S_W + 5 * 16384;  na.b[4] = d_in[19];  // P3
  na.W[5] = stg + S_W + 6 * 16384;  na.b[5] = d_in[21];  // D1
  na.W[6] = stg + S_W + 7 * 16384;  na.b[6] = d_in[23];  // D2
  na.W[7] = stg + S_WT;             na.b[7] = d_in[27];  // T
  na.out[0] = ws + F_V1H; na.out[1] = ws + F_V2H; na.out[2] = ws + F_P1H;
  na.out[3] = ws + F_P2H; na.out[4] = ws + F_P3H; na.out[5] = ws + F_D1H;
  na.out[6] = ws + F_D2H; na.out[7] = ws + F_G;
  na.flags = flags;
  node_gemm_kernel<<<dim3((NN + 63) / 64, 8), 256, 0, stream>>>(na);

  edge_kernel<<<NE / 64, 256, 0, stream>>>(
      d_in[1], stg + S_H, spatial, src, dst,
      stg + S_W + 2 * 16384, stg + S_W + 8 * 16384, d_in[13], d_in[25],
      ws + F_P1H, ws + F_P2H, ws + F_FAB, d_out, flags);

  node_out_kernel<<<NN / 4, 256, 0, stream>>>(
      stg + S_H, stg + S_P, stg + S_D, d_in[4],
      ws + F_V1H, ws + F_V2H, ws + F_P3H, ws + F_D1H, ws + F_D2H, ws + F_G,
      ws + F_FAB, ws + F_CNT, d_out, flags);
}